// Round 1
// 573.084 us; speedup vs baseline: 1.1487x; 1.1487x over previous
//
#include <hip/hip_runtime.h>
#include <cstddef>

#define NE 16384
#define NN 4096
#define BG 16
#define NT 16      // nodes per conv tile
#define ACH 16     // a-chunk size (4 chunks of 16 = 64)

__device__ __forceinline__ float lrelu(float v){ return v >= 0.f ? v : 0.01f*v; }
__device__ __forceinline__ float sigm(float v){ return 1.f/(1.f + expf(-v)); }

// ---------------- setup: WihT, WhhT, h0, he, deg(dst), cnt(src) ----------------
__global__ __launch_bounds__(256) void setup_kernel(
    const float* __restrict__ x, const float* __restrict__ ea,
    const int* __restrict__ ei,
    const float* __restrict__ W0, const float* __restrict__ b0,
    const float* __restrict__ We1, const float* __restrict__ be1,
    const float* __restrict__ Wih, const float* __restrict__ Whh,
    float* __restrict__ WihT, float* __restrict__ WhhT,
    float* __restrict__ h, float* __restrict__ he,
    int* __restrict__ deg, int* __restrict__ cnt)
{
    int t = blockIdx.x*256 + threadIdx.x;   // grid: 4096x256 = 1048576
    {   // he: [E,64]  lrelu(edge_attr @ We1 + be1)
        int e = t >> 6, f = t & 63;
        float v = be1[f];
        #pragma unroll
        for (int d = 0; d < 4; ++d) v += ea[e*4+d]*We1[d*64+f];
        he[t] = lrelu(v);
    }
    if (t < NN*64) {    // h0 = lrelu(x @ W0 + b0)
        int n = t >> 6, f = t & 63;
        float v = b0[f];
        #pragma unroll
        for (int d = 0; d < 3; ++d) v += x[n*3+d]*W0[d*64+f];
        h[t] = lrelu(v);
    }
    if (t < 12288) {    // WihT[k][g] = Wih[g][k], WhhT[k][g] = Whh[g][k]
        int k = t / 192, g = t - k*192;
        WihT[t] = Wih[g*64 + k];
        WhhT[t] = Whh[g*64 + k];
    }
    if (t < NE) {
        atomicAdd(&deg[ei[NE + t]], 1);   // in-degree (dst) for mean aggr
        atomicAdd(&cnt[ei[t]], 1);        // out-degree (src) for edge sort
    }
}

// ---------------- exclusive scan of cnt[4096] -> offs[4097] (1 block) ----------------
__global__ __launch_bounds__(256) void scan_kernel(const int* __restrict__ cnt,
                                                   int* __restrict__ offs)
{
    __shared__ int ps[256];
    int t = threadIdx.x;
    int base = t*16;
    int loc[16];
    int s = 0;
    #pragma unroll
    for (int i = 0; i < 16; ++i) { loc[i] = s; s += cnt[base+i]; }
    ps[t] = s; __syncthreads();
    for (int off = 1; off < 256; off <<= 1) {
        int v = 0;
        if (t >= off) v = ps[t-off];
        __syncthreads();
        if (t >= off) ps[t] += v;
        __syncthreads();
    }
    int pre = (t == 0) ? 0 : ps[t-1];
    #pragma unroll
    for (int i = 0; i < 16; ++i) offs[base+i] = pre + loc[i];
    if (t == 255) offs[NN] = pre + s;
}

// ---------------- scatter: build src-sorted edge arrays ----------------
__global__ __launch_bounds__(256) void scatter_kernel(
    const int* __restrict__ ei, const int* __restrict__ offs,
    int* __restrict__ cnt,  // consumed as cursor via atomicSub
    int* __restrict__ srcs, int* __restrict__ dsts, int* __restrict__ perm)
{
    int e = blockIdx.x*256 + threadIdx.x;
    if (e >= NE) return;
    int s = ei[e], d = ei[NE + e];
    int old = atomicSub(&cnt[s], 1);
    int pos = offs[s] + old - 1;
    srcs[pos] = s; dsts[pos] = d; perm[pos] = e;
}

// ---------------- gather he rows into src-sorted order ----------------
__global__ __launch_bounds__(256) void reorder_kernel(
    const float* __restrict__ he, const int* __restrict__ perm,
    float* __restrict__ he_srt)
{
    int t = blockIdx.x*256 + threadIdx.x;   // 4096 x 256 = NE*64
    he_srt[t] = he[(size_t)perm[t>>6]*64 + (t & 63)];
}

// ---------------- inv_deg + per-graph node ranges ----------------
__global__ __launch_bounds__(256) void inv_range_kernel(
    const int* __restrict__ deg, const int* __restrict__ batch,
    float* __restrict__ inv_deg, int* __restrict__ gstart, int* __restrict__ gend)
{
    int n = blockIdx.x*256 + threadIdx.x;   // 16 blocks -> 4096
    if (n >= NN) return;
    inv_deg[n] = 1.f / fmaxf((float)deg[n], 1.f);
    int b  = batch[n];
    int bp = (n == 0)    ? -1 : batch[n-1];
    int bn = (n == NN-1) ? BG : batch[n+1];
    for (int g = bp+1; g <= b; ++g) gstart[g] = n;
    for (int g = b;   g <  bn; ++g) gend[g]   = n+1;
    if (n == 0)    for (int g = 0;   g < b;  ++g) gend[g]   = 0;
    if (n == NN-1) for (int g = b+1; g < BG; ++g) gstart[g] = NN;
}

// ---------------- fused per-iteration conv: T-in-LDS + edge messages ----------------
// Block = 16 src nodes, 1024 threads. T[n][a][f] computed 16 a-values at a time
// in LDS; the tile's (contiguous, src-sorted) out-edges consume each chunk
// immediately, accumulating msg in registers; one atomic scatter per edge.
__global__ __launch_bounds__(1024) void conv_kernel(
    const float* __restrict__ h, const float* __restrict__ We2,
    const float* __restrict__ be2, const float* __restrict__ he_srt,
    const int* __restrict__ offs, const int* __restrict__ srcs,
    const int* __restrict__ dsts, float* __restrict__ agg)
{
    __shared__ float hsT[64][NT];         // [i][n]            4 KB
    __shared__ float Tb [NT][64];         // msg bias per node 4 KB
    __shared__ float Tc [ACH][NT][64];    // T chunk           64 KB
    int t  = threadIdx.x;
    int n0 = blockIdx.x * NT;

    {   // stage h tile transposed
        int n = t >> 6, i = t & 63;
        hsT[i][n] = h[(size_t)(n0+n)*64 + i];
    }
    __syncthreads();
    {   // Tb[n][f] = sum_i h[n,i] * be2[i*64+f]
        int n = t >> 6, f = t & 63;
        float acc = 0.f;
        #pragma unroll 8
        for (int i = 0; i < 64; ++i) acc += hsT[i][n] * be2[i*64+f];
        Tb[n][f] = acc;
    }

    // this tile's out-edges (contiguous in src-sorted arrays)
    int ebase = offs[n0];
    int ecnt  = offs[n0+NT] - ebase;
    int eend  = ebase + ecnt;
    int slot  = t >> 4;            // 0..63 edge slots
    int f4    = (t & 15) * 4;      // 4 output features per thread
    int e0 = ebase + slot, e1 = ebase + slot + 64;
    int nl0 = -1, dt0 = 0, nl1 = -1, dt1 = 0;
    if (slot < ecnt)       { nl0 = srcs[e0] - n0; dt0 = dsts[e0]; }
    if (slot + 64 < ecnt)  { nl1 = srcs[e1] - n0; dt1 = dsts[e1]; }
    float4 m0 = {0,0,0,0}, m1 = {0,0,0,0};

    // T-stage thread mapping
    int aT = t >> 6;               // 0..15  a' within chunk
    int fT = (t & 15) * 4;         // 4 f per thread
    int nT = ((t >> 4) & 3) * 4;   // 4 n per thread

    for (int c = 0; c < 4; ++c) {
        // ---- compute T chunk into registers (reads hsT + global We2 only) ----
        const float* Wp = We2 + ((size_t)(c*ACH + aT))*4096 + fT;
        float4 A0 = {0,0,0,0}, A1 = {0,0,0,0}, A2 = {0,0,0,0}, A3 = {0,0,0,0};
        #pragma unroll 8
        for (int i = 0; i < 64; ++i) {
            float4 w  = *(const float4*)(Wp + (size_t)i*64);
            float4 hv = *(const float4*)&hsT[i][nT];
            A0.x += hv.x*w.x; A0.y += hv.x*w.y; A0.z += hv.x*w.z; A0.w += hv.x*w.w;
            A1.x += hv.y*w.x; A1.y += hv.y*w.y; A1.z += hv.y*w.z; A1.w += hv.y*w.w;
            A2.x += hv.z*w.x; A2.y += hv.z*w.y; A2.z += hv.z*w.z; A2.w += hv.z*w.w;
            A3.x += hv.w*w.x; A3.y += hv.w*w.y; A3.z += hv.w*w.z; A3.w += hv.w*w.w;
        }
        __syncthreads();   // previous chunk's edge reads done (and Tb visible)
        *(float4*)&Tc[aT][nT+0][fT] = A0;
        *(float4*)&Tc[aT][nT+1][fT] = A1;
        *(float4*)&Tc[aT][nT+2][fT] = A2;
        *(float4*)&Tc[aT][nT+3][fT] = A3;
        __syncthreads();   // chunk ready

        // ---- edge stage: accumulate partial msg in registers ----
        if (nl0 >= 0) {
            const float* hep = he_srt + (size_t)e0*64 + c*ACH;
            #pragma unroll
            for (int a = 0; a < ACH; ++a) {
                float hv = hep[a];
                float4 tv = *(const float4*)&Tc[a][nl0][f4];
                m0.x += hv*tv.x; m0.y += hv*tv.y; m0.z += hv*tv.z; m0.w += hv*tv.w;
            }
        }
        if (nl1 >= 0) {
            const float* hep = he_srt + (size_t)e1*64 + c*ACH;
            #pragma unroll
            for (int a = 0; a < ACH; ++a) {
                float hv = hep[a];
                float4 tv = *(const float4*)&Tc[a][nl1][f4];
                m1.x += hv*tv.x; m1.y += hv*tv.y; m1.z += hv*tv.z; m1.w += hv*tv.w;
            }
        }
        // overflow fallback (>128 edges in a tile): direct per-chunk atomics
        for (int e = ebase + 128 + slot; e < eend; e += 64) {
            int nl = srcs[e] - n0, dt = dsts[e];
            const float* hep = he_srt + (size_t)e*64 + c*ACH;
            float4 pm = {0,0,0,0};
            #pragma unroll
            for (int a = 0; a < ACH; ++a) {
                float hv = hep[a];
                float4 tv = *(const float4*)&Tc[a][nl][f4];
                pm.x += hv*tv.x; pm.y += hv*tv.y; pm.z += hv*tv.z; pm.w += hv*tv.w;
            }
            if (c == 0) {
                float4 b = *(const float4*)&Tb[nl][f4];
                pm.x += b.x; pm.y += b.y; pm.z += b.z; pm.w += b.w;
            }
            float* ap = agg + (size_t)dt*64 + f4;
            atomicAdd(ap+0, pm.x); atomicAdd(ap+1, pm.y);
            atomicAdd(ap+2, pm.z); atomicAdd(ap+3, pm.w);
        }
    }

    // ---- scatter: one atomic add per edge (msg + bias) ----
    if (nl0 >= 0) {
        float4 b = *(const float4*)&Tb[nl0][f4];
        float* ap = agg + (size_t)dt0*64 + f4;
        atomicAdd(ap+0, m0.x+b.x); atomicAdd(ap+1, m0.y+b.y);
        atomicAdd(ap+2, m0.z+b.z); atomicAdd(ap+3, m0.w+b.w);
    }
    if (nl1 >= 0) {
        float4 b = *(const float4*)&Tb[nl1][f4];
        float* ap = agg + (size_t)dt1*64 + f4;
        atomicAdd(ap+0, m1.x+b.x); atomicAdd(ap+1, m1.y+b.y);
        atomicAdd(ap+2, m1.z+b.z); atomicAdd(ap+3, m1.w+b.w);
    }
}

// ---------------- per-iteration node kernel: m, gi, gh GEMMs + GRU ----------------
// 32 nodes per block, 512 threads, 128 blocks. Computes mroot/gh from h directly
// (no C buffer). Zeroes agg after consuming it (ready for next conv).
__global__ __launch_bounds__(512) void node_kernel(
    const float* __restrict__ WihT, const float* __restrict__ WhhT,
    const float* __restrict__ root, const float* __restrict__ conv_b,
    const float* __restrict__ inv_deg, const float* __restrict__ bih,
    const float* __restrict__ bhh, float* __restrict__ h,
    float* __restrict__ agg)
{
    __shared__ float WT[64][392];   // cols 0..191: WihT, 196..387: WhhT  (~100 KB)
    __shared__ float hT[64][34];
    __shared__ float mT[64][34];
    int t  = threadIdx.x;
    int n0 = blockIdx.x * 32;

    #pragma unroll
    for (int i = 0; i < 24; ++i) {  // stage both weight blocks (12288 each)
        int idx = t + i*512;
        int k = idx / 192, c = idx - k*192;
        WT[k][c]       = WihT[idx];
        WT[k][196 + c] = WhhT[idx];
    }
    #pragma unroll
    for (int i = 0; i < 4; ++i) {   // stage h tile transposed
        int idx = t + i*512;
        int n = idx >> 6, d = idx & 63;
        hT[d][n] = h[(size_t)(n0+n)*64 + d];
    }
    __syncthreads();
    #pragma unroll
    for (int i = 0; i < 4; ++i) {   // m = lrelu(agg*inv_deg + h@root + conv_b)
        int idx = t + i*512;
        int n = idx >> 6, d = idx & 63;
        int gn = n0 + n;
        float v = agg[(size_t)gn*64 + d]*inv_deg[gn] + conv_b[d];
        agg[(size_t)gn*64 + d] = 0.f;          // ready for next iteration's conv
        #pragma unroll 8
        for (int k = 0; k < 64; ++k) v += hT[k][n]*root[k*64 + d];
        mT[d][n] = lrelu(v);
    }
    __syncthreads();

    int tx = t & 31, ty = t >> 5;   // g2 = 2*tx, n2 = 2*ty
    float ai[2][2][3] = {{{0.f}}};
    float ah[2][2][3] = {{{0.f}}};
    #pragma unroll 8
    for (int k = 0; k < 64; ++k) {
        float2 am = *(float2*)&mT[k][ty*2];
        float2 av = *(float2*)&hT[k][ty*2];
        #pragma unroll
        for (int g = 0; g < 3; ++g) {
            float2 bi = *(float2*)&WT[k][g*64 + tx*2];
            float2 bh = *(float2*)&WT[k][196 + g*64 + tx*2];
            ai[0][0][g] += am.x*bi.x; ai[0][1][g] += am.x*bi.y;
            ai[1][0][g] += am.y*bi.x; ai[1][1][g] += am.y*bi.y;
            ah[0][0][g] += av.x*bh.x; ah[0][1][g] += av.x*bh.y;
            ah[1][0][g] += av.y*bh.x; ah[1][1][g] += av.y*bh.y;
        }
    }
    #pragma unroll
    for (int i = 0; i < 2; ++i) {
        int n = ty*2 + i, gn = n0 + n;
        #pragma unroll
        for (int j = 0; j < 2; ++j) {
            int g = tx*2 + j;
            float r  = sigm(ai[i][j][0] + bih[g]      + ah[i][j][0] + bhh[g]);
            float z  = sigm(ai[i][j][1] + bih[64+g]   + ah[i][j][1] + bhh[64+g]);
            float nn = tanhf(ai[i][j][2] + bih[128+g] + r*(ah[i][j][2] + bhh[128+g]));
            float ho = hT[g][n];
            h[(size_t)gn*64 + g] = (1.f - z)*nn + z*ho;
        }
    }
}

// ---------------- finale ----------------
__device__ __forceinline__ float q_val(const float* lbih, const float* lbhh, int g)
{
    float gi = lbih[g]     + lbhh[g];
    float gg = lbih[128+g] + lbhh[128+g];
    float go = lbih[192+g] + lbhh[192+g];
    return sigm(go)*tanhf(sigm(gi)*tanhf(gg));   // hl0=cl0=q_star0=0
}

__global__ __launch_bounds__(256) void e_kernel(
    const float* __restrict__ h, const float* __restrict__ lbih,
    const float* __restrict__ lbhh, float* __restrict__ e)
{
    __shared__ float qs[64];
    int t = threadIdx.x;
    if (t < 64) qs[t] = q_val(lbih, lbhh, t);
    __syncthreads();
    int w = t >> 6, f = t & 63;
    int n = blockIdx.x*4 + w;
    float p = h[(size_t)n*64 + f]*qs[f];
    #pragma unroll
    for (int off = 32; off; off >>= 1) p += __shfl_xor(p, off);
    if (f == 0) e[n] = p;
}

__global__ __launch_bounds__(1024) void pool_kernel(
    const float* __restrict__ h, float* __restrict__ e,
    const int* __restrict__ gstart, const int* __restrict__ gend,
    const float* __restrict__ lbih, const float* __restrict__ lbhh,
    const float* __restrict__ Wout, const float* __restrict__ bout,
    float* __restrict__ out)
{
    __shared__ float red[1024];
    __shared__ float rp[64];
    __shared__ float sval;
    int g = blockIdx.x, t = threadIdx.x;
    int s = gstart[g], en = gend[g];

    float mx = -1e30f;
    for (int n = s+t; n < en; n += 1024) mx = fmaxf(mx, e[n]);
    red[t] = mx; __syncthreads();
    for (int st = 512; st; st >>= 1) { if (t < st) red[t] = fmaxf(red[t], red[t+st]); __syncthreads(); }
    if (t == 0) sval = red[0];
    __syncthreads();
    float lmx = sval;
    __syncthreads();

    float sm = 0.f;
    for (int n = s+t; n < en; n += 1024) { float a = expf(e[n]-lmx); e[n] = a; sm += a; }
    red[t] = sm; __syncthreads();
    for (int st = 512; st; st >>= 1) { if (t < st) red[t] += red[t+st]; __syncthreads(); }
    if (t == 0) sval = (red[0] > 0.f) ? 1.f/red[0] : 0.f;
    __syncthreads();
    float inv_asum = sval;
    __syncthreads();

    int w = t >> 6, f = t & 63;
    float racc = 0.f;
    for (int n = s+w; n < en; n += 16) racc += e[n]*h[(size_t)n*64 + f];
    red[t] = racc; __syncthreads();
    if (w == 0) {
        float a = 0.f;
        #pragma unroll
        for (int i = 0; i < 16; ++i) a += red[i*64 + f];
        rp[f] = a*inv_asum;
    }
    __syncthreads();

    if (t < 64) {
        float qv = q_val(lbih, lbhh, t);
        float p0 = qv*Wout[t*2]   + rp[t]*Wout[(64+t)*2];
        float p1 = qv*Wout[t*2+1] + rp[t]*Wout[(64+t)*2+1];
        #pragma unroll
        for (int off = 32; off; off >>= 1) { p0 += __shfl_xor(p0, off); p1 += __shfl_xor(p1, off); }
        if (t == 0) { out[g*2] = p0 + bout[0]; out[g*2+1] = p1 + bout[1]; }
    }
}

extern "C" void kernel_launch(void* const* d_in, const int* in_sizes, int n_in,
                              void* d_out, int out_size, void* d_ws, size_t ws_size,
                              hipStream_t stream)
{
    const float* x      = (const float*)d_in[0];
    const float* ea     = (const float*)d_in[1];
    const int*   ei     = (const int*)  d_in[2];
    const int*   batch  = (const int*)  d_in[3];
    const float* W0     = (const float*)d_in[4];
    const float* b0     = (const float*)d_in[5];
    const float* We1    = (const float*)d_in[6];
    const float* be1    = (const float*)d_in[7];
    const float* We2    = (const float*)d_in[8];
    const float* be2    = (const float*)d_in[9];
    const float* root   = (const float*)d_in[10];
    const float* conv_b = (const float*)d_in[11];
    const float* Wih    = (const float*)d_in[12];
    const float* Whh    = (const float*)d_in[13];
    const float* bih    = (const float*)d_in[14];
    const float* bhh    = (const float*)d_in[15];
    const float* lbih   = (const float*)d_in[18];
    const float* lbhh   = (const float*)d_in[19];
    const float* Wout   = (const float*)d_in[20];
    const float* bout   = (const float*)d_in[21];
    float* out = (float*)d_out;

    float* W = (float*)d_ws;
    size_t off = 0;
    float* h       = W + off; off += (size_t)NN*64;
    float* he      = W + off; off += (size_t)NE*64;
    float* he_srt  = W + off; off += (size_t)NE*64;
    float* agg     = W + off; off += (size_t)NN*64;
    float* WihT    = W + off; off += 12288;
    float* WhhT    = W + off; off += 12288;
    float* inv_deg = W + off; off += NN;
    float* e       = W + off; off += NN;
    int*   deg     = (int*)(W + off); off += NN;   // deg+cnt contiguous: one memset
    int*   cnt     = (int*)(W + off); off += NN;
    int*   offs    = (int*)(W + off); off += NN+1;
    int*   srcs    = (int*)(W + off); off += NE;
    int*   dsts    = (int*)(W + off); off += NE;
    int*   perm    = (int*)(W + off); off += NE;
    int*   gstart  = (int*)(W + off); off += BG;
    int*   gend    = (int*)(W + off); off += BG;

    hipMemsetAsync(deg, 0, 2*NN*sizeof(int), stream);
    hipMemsetAsync(agg, 0, (size_t)NN*64*sizeof(float), stream);
    setup_kernel<<<4096, 256, 0, stream>>>(x, ea, ei, W0, b0, We1, be1, Wih, Whh,
                                           WihT, WhhT, h, he, deg, cnt);
    scan_kernel<<<1, 256, 0, stream>>>(cnt, offs);
    scatter_kernel<<<64, 256, 0, stream>>>(ei, offs, cnt, srcs, dsts, perm);
    reorder_kernel<<<4096, 256, 0, stream>>>(he, perm, he_srt);
    inv_range_kernel<<<16, 256, 0, stream>>>(deg, batch, inv_deg, gstart, gend);

    for (int it = 0; it < 6; ++it) {
        conv_kernel<<<NN/NT, 1024, 0, stream>>>(h, We2, be2, he_srt,
                                                offs, srcs, dsts, agg);
        node_kernel<<<NN/32, 512, 0, stream>>>(WihT, WhhT, root, conv_b,
                                               inv_deg, bih, bhh, h, agg);
    }

    e_kernel<<<NN/4, 256, 0, stream>>>(h, lbih, lbhh, e);
    pool_kernel<<<BG, 1024, 0, stream>>>(h, e, gstart, gend, lbih, lbhh, Wout, bout, out);
}